// Round 4
// baseline (5237.716 us; speedup 1.0000x reference)
//
#include <hip/hip_runtime.h>

#define DEVINL __device__ __forceinline__

typedef __attribute__((ext_vector_type(4))) float f32x4;
typedef __attribute__((ext_vector_type(8))) short s16x8;
typedef __attribute__((ext_vector_type(4))) unsigned short u16x4;
typedef __attribute__((ext_vector_type(8))) unsigned short u16x8;

static constexpr int HDIM = 4000;    // hidden
static constexpr int G4   = 16000;   // 4*H
static constexpr int FD   = 1024;    // feature dim
static constexpr int LD0  = 5024;    // W_ih0 row stride
static constexpr int TT   = 31;      // timesteps computed
static constexpr int NJ   = 64 * 31; // (b,t) pairs
static constexpr int KCT  = 125;     // k-chunks (32 wide) per K=4000
static constexpr unsigned NBLK = 250;

DEVINL float bf2f(unsigned short u) {
  unsigned v = (unsigned)u << 16;
  return __builtin_bit_cast(float, v);
}
DEVINL unsigned short f2bf(float x) {
  unsigned u = __builtin_bit_cast(unsigned, x);
  u += 0x7fffu + ((u >> 16) & 1u);          // RNE, no NaNs in this problem
  return (unsigned short)(u >> 16);
}
DEVINL float sigm(float x) { return 1.f / (1.f + __expf(-x)); }
DEVINL float tanh_(float x) { float e = __expf(2.f * x); return (e - 1.f) / (e + 1.f); }

// ---------- packed-layout GEMM ----------
// A: pW chunk layout [o][lane][8], o = (rb*4+g)*125 + kc.  1 KB/instr, sequential.
// B: hP layout [k8][64][8]; 4 frags of one iter = one contiguous 4 KB span.
// k-permutation (k = 8*lg+e within chunk) identical on A and B -> cancels.
DEVINL void gemmP(const unsigned short* __restrict__ Wp,
                  const unsigned short* __restrict__ hP,
                  int kc0, int kc1, int lane, int lr, int lg, f32x4* acc) {
  const unsigned short* wp = Wp + (size_t)kc0 * 512 + lane * 8;
  const unsigned short* bp = hP + (size_t)kc0 * 2048 + (lg * 64 + lr) * 8;
  #pragma unroll 2
  for (int kc = kc0; kc < kc1; ++kc) {
    s16x8 a  = *(const s16x8*)wp;
    s16x8 b0 = *(const s16x8*)(bp);
    s16x8 b1 = *(const s16x8*)(bp + 128);
    s16x8 b2 = *(const s16x8*)(bp + 256);
    s16x8 b3 = *(const s16x8*)(bp + 384);
    wp += 512; bp += 2048;
    acc[0] = __builtin_amdgcn_mfma_f32_16x16x32_bf16(a, b0, acc[0], 0, 0, 0);
    acc[1] = __builtin_amdgcn_mfma_f32_16x16x32_bf16(a, b1, acc[1], 0, 0, 0);
    acc[2] = __builtin_amdgcn_mfma_f32_16x16x32_bf16(a, b2, acc[2], 0, 0, 0);
    acc[3] = __builtin_amdgcn_mfma_f32_16x16x32_bf16(a, b3, acc[3], 0, 0, 0);
  }
}

// ---------- row-major-B GEMM (featpre only) ----------
DEVINL void gemm16u(const unsigned short* __restrict__ W,
                    const unsigned short* __restrict__ Hb,
                    int K, int kbeg, int kend, int lr, int lg, f32x4* acc) {
  const unsigned short* wp  = W  + (size_t)lr * K + 8 * lg + kbeg;
  const unsigned short* hp0 = Hb + (size_t)lr * K + 8 * lg + kbeg;
  const unsigned short* hp1 = hp0 + (size_t)16 * K;
  const unsigned short* hp2 = hp0 + (size_t)32 * K;
  const unsigned short* hp3 = hp0 + (size_t)48 * K;
  int nk = kend - kbeg;
  #pragma unroll 2
  for (int k = 0; k < nk; k += 32) {
    s16x8 a  = *(const s16x8*)(wp  + k);
    s16x8 b0 = *(const s16x8*)(hp0 + k);
    s16x8 b1 = *(const s16x8*)(hp1 + k);
    s16x8 b2 = *(const s16x8*)(hp2 + k);
    s16x8 b3 = *(const s16x8*)(hp3 + k);
    acc[0] = __builtin_amdgcn_mfma_f32_16x16x32_bf16(a, b0, acc[0], 0, 0, 0);
    acc[1] = __builtin_amdgcn_mfma_f32_16x16x32_bf16(a, b1, acc[1], 0, 0, 0);
    acc[2] = __builtin_amdgcn_mfma_f32_16x16x32_bf16(a, b2, acc[2], 0, 0, 0);
    acc[3] = __builtin_amdgcn_mfma_f32_16x16x32_bf16(a, b3, acc[3], 0, 0, 0);
  }
}

__global__ void to_bf16_k(const float* __restrict__ s, unsigned short* __restrict__ d, long n) {
  long i = (((long)blockIdx.x * blockDim.x) + threadIdx.x) * 8;
  if (i >= n) return;
  f32x4 a = *(const f32x4*)(s + i);
  f32x4 b = *(const f32x4*)(s + i + 4);
  u16x8 o;
  o[0] = f2bf(a[0]); o[1] = f2bf(a[1]); o[2] = f2bf(a[2]); o[3] = f2bf(a[3]);
  o[4] = f2bf(b[0]); o[5] = f2bf(b[1]); o[6] = f2bf(b[2]); o[7] = f2bf(b[3]);
  *(u16x8*)(d + i) = o;
}

// pack W [16000][4000] f32 -> fragment-linear bf16 chunks
__global__ __launch_bounds__(256) void pack_k(const float* __restrict__ W,
                                              unsigned short* __restrict__ P) {
  int wv = (blockIdx.x << 2) + (threadIdx.x >> 6);    // chunk id 0..124999
  int lane = threadIdx.x & 63, lr = lane & 15, lg = lane >> 4;
  int rb = wv / 500; int rem = wv - rb * 500;
  int g = rem / KCT; int kc = rem - g * KCT;
  int row = g * 4000 + rb * 16 + lr;
  int col = kc * 32 + lg * 8;
  const float* sp = W + (size_t)row * 4000 + col;
  f32x4 a = *(const f32x4*)sp;
  f32x4 b = *(const f32x4*)(sp + 4);
  u16x8 o;
  o[0] = f2bf(a[0]); o[1] = f2bf(a[1]); o[2] = f2bf(a[2]); o[3] = f2bf(a[3]);
  o[4] = f2bf(b[0]); o[5] = f2bf(b[1]); o[6] = f2bf(b[2]); o[7] = f2bf(b[3]);
  *(u16x8*)(P + ((size_t)wv * 64 + lane) * 8) = o;
}

// W_f = W_ih0[:, :1024] (strided rows) -> bf16 [16000][1024]
__global__ void wf_conv_k(const float* __restrict__ s, unsigned short* __restrict__ d) {
  int idx = blockIdx.x * blockDim.x + threadIdx.x;   // 16000*128
  int r = idx >> 7;
  int k8 = (idx & 127) << 3;
  const float* sp = s + (size_t)r * LD0 + k8;
  f32x4 a = *(const f32x4*)sp;
  f32x4 b = *(const f32x4*)(sp + 4);
  u16x8 o;
  o[0] = f2bf(a[0]); o[1] = f2bf(a[1]); o[2] = f2bf(a[2]); o[3] = f2bf(a[3]);
  o[4] = f2bf(b[0]); o[5] = f2bf(b[1]); o[6] = f2bf(b[2]); o[7] = f2bf(b[3]);
  *(u16x8*)(d + (size_t)r * FD + k8) = o;
}

// fp0[b][r] = b_ih0[r] + sum_k feat[b][k] * Wf[r][k]
__global__ __launch_bounds__(512, 2) void featpre_k(
    const unsigned short* __restrict__ Wf, const unsigned short* __restrict__ Fb,
    const float* __restrict__ bih0, float* __restrict__ fp0) {
  __shared__ float gl[2][4][16][64];
  int tid = threadIdx.x, lane = tid & 63, wid = tid >> 6;
  int lr = lane & 15, lg = lane >> 4;
  int sub = wid & 3, kh = wid >> 2;
  int rowblk = blockIdx.x << 6;
  size_t row0 = (size_t)rowblk + (sub << 4);
  f32x4 acc[4] = {};
  gemm16u(Wf + row0 * FD, Fb, FD, kh ? 512 : 0, kh ? 1024 : 512, lr, lg, acc);
  #pragma unroll
  for (int n0 = 0; n0 < 4; ++n0)
    #pragma unroll
    for (int e = 0; e < 4; ++e)
      gl[kh][sub][4 * lg + e][(n0 << 4) + lr] = acc[n0][e];
  __syncthreads();
  for (int n = tid; n < 4096; n += 512) {
    int i = n & 63, b = n >> 6;
    int r = rowblk + i;
    float v = gl[0][i >> 4][i & 15][b] + gl[1][i >> 4][i & 15][b] + bih0[r];
    fp0[(size_t)b * G4 + r] = v;
  }
}

// ih0T[r][j] = bf16( fp0[b][r] + W_v[r][tok(b,t)] ), j = b*31+t  (coalesced)
__global__ __launch_bounds__(256) void gather_k(
    const float* __restrict__ Wih0, const int* __restrict__ caps,
    const float* __restrict__ fp0, unsigned short* __restrict__ ih0T) {
  __shared__ unsigned short wv[4][4000];
  int r0 = blockIdx.x << 2;
  for (int rr = 0; rr < 4; ++rr) {
    const float* src = Wih0 + (size_t)(r0 + rr) * LD0 + FD;
    for (int c4 = threadIdx.x; c4 < 1000; c4 += 256) {
      f32x4 v = *(const f32x4*)(src + c4 * 4);
      u16x4 o;
      o[0] = f2bf(v[0]); o[1] = f2bf(v[1]); o[2] = f2bf(v[2]); o[3] = f2bf(v[3]);
      *(u16x4*)(&wv[rr][c4 * 4]) = o;
    }
  }
  __syncthreads();
  for (int j = threadIdx.x; j < NJ; j += 256) {
    int b = j / TT, t = j - b * TT;
    int tok = caps[(b << 5) + t];
    f32x4 f = *(const f32x4*)(fp0 + (size_t)b * G4 + r0);
    #pragma unroll
    for (int rr = 0; rr < 4; ++rr)
      ih0T[(size_t)(r0 + rr) * NJ + j] = f2bf(f[rr] + bf2f(wv[rr][tok]));
  }
}

// transpose ih0T [16000][1984] -> ih0J [1984][16000]
__global__ __launch_bounds__(256) void tj_k(const unsigned short* __restrict__ src,
                                            unsigned short* __restrict__ dst) {
  __shared__ unsigned short tile[32][34];
  int r0 = blockIdx.x << 5;      // 500 tiles
  int j0 = blockIdx.y << 5;      // 62 tiles
  int c = threadIdx.x & 31, q = threadIdx.x >> 5;
  #pragma unroll
  for (int e = 0; e < 4; ++e) {
    int rr = q + e * 8;
    tile[rr][c] = src[(size_t)(r0 + rr) * NJ + j0 + c];
  }
  __syncthreads();
  #pragma unroll
  for (int e = 0; e < 4; ++e) {
    int jj = q + e * 8;
    dst[(size_t)(j0 + jj) * G4 + r0 + c] = tile[c][jj];
  }
}

DEVINL size_t hpk(int r, int b) {          // packed h index [k8][64][8]
  return ((size_t)(r >> 3) * 64 + b) * 8 + (r & 7);
}

// sense-reversing grid barrier (device-scope; all NBLK blocks co-resident)
DEVINL void gridbar(unsigned* cnt, unsigned* gen) {
  __syncthreads();
  if (threadIdx.x == 0) {
    __threadfence();                                     // release prior writes
    unsigned g = __hip_atomic_load(gen, __ATOMIC_RELAXED, __HIP_MEMORY_SCOPE_AGENT);
    unsigned a = __hip_atomic_fetch_add(cnt, 1u, __ATOMIC_ACQ_REL, __HIP_MEMORY_SCOPE_AGENT);
    if (a == NBLK - 1u) {
      __hip_atomic_store(cnt, 0u, __ATOMIC_RELAXED, __HIP_MEMORY_SCOPE_AGENT);
      __hip_atomic_fetch_add(gen, 1u, __ATOMIC_RELEASE, __HIP_MEMORY_SCOPE_AGENT);
    } else {
      while (__hip_atomic_load(gen, __ATOMIC_ACQUIRE, __HIP_MEMORY_SCOPE_AGENT) == g) {
        __builtin_amdgcn_s_sleep(8);
      }
    }
    __threadfence();                                     // acquire others' writes
  }
  __syncthreads();
}

__global__ __launch_bounds__(1024, 4) void lstm_persist_k(
    const unsigned short* __restrict__ pWhh0, const unsigned short* __restrict__ pWih1,
    const unsigned short* __restrict__ pWhh1,
    unsigned short* __restrict__ h0b, unsigned short* __restrict__ h1b,
    float* __restrict__ c0, float* __restrict__ c1,
    const unsigned short* __restrict__ ih0J,
    const float* __restrict__ bhh0, const float* __restrict__ bih1,
    const float* __restrict__ bhh1, float* __restrict__ out,
    unsigned* __restrict__ bar) {
  __shared__ float gl[2][4][16][64];
  int tid = threadIdx.x, lane = tid & 63, wid = tid >> 6;   // wid 0..15
  int lr = lane & 15, lg = lane >> 4;
  int gate = wid & 3, kq = wid >> 2;
  int wg16 = blockIdx.x << 4;
  int kc0 = 31 * kq, kc1 = (kq == 3) ? KCT : kc0 + 31;
  int i = tid & 15, bb = tid >> 4;                          // epilogue mapping
  int r = wg16 + i;
  size_t ci = (size_t)bb * HDIM + r;
  size_t wo = ((size_t)(blockIdx.x * 4 + gate) * KCT) * 512;
  unsigned* cnt = bar;
  unsigned* gen = bar + 32;

  for (int t = 0; t < TT; ++t) {
    const unsigned short* h0_in  = h0b + (size_t)(t & 1) * 256000;
    unsigned short*       h0_out = h0b + (size_t)((t + 1) & 1) * 256000;
    const unsigned short* h1_in  = h1b + (size_t)(t & 1) * 256000;
    unsigned short*       h1_out = h1b + (size_t)((t + 1) & 1) * 256000;

    // ---------------- layer 0 ----------------
    {
      f32x4 acc[4] = {};
      gemmP(pWhh0 + wo, h0_in, kc0, kc1, lane, lr, lg, acc);
      if (kq < 2) {
        #pragma unroll
        for (int n0 = 0; n0 < 4; ++n0)
          #pragma unroll
          for (int e = 0; e < 4; ++e)
            gl[kq][gate][4 * lg + e][(n0 << 4) + lr] = acc[n0][e];
      }
      __syncthreads();
      if (kq >= 2) {
        #pragma unroll
        for (int n0 = 0; n0 < 4; ++n0)
          #pragma unroll
          for (int e = 0; e < 4; ++e)
            gl[kq - 2][gate][4 * lg + e][(n0 << 4) + lr] += acc[n0][e];
      }
      __syncthreads();
      const unsigned short* ih = ih0J + (size_t)(bb * TT + t) * G4;
      float gi = gl[0][0][i][bb] + gl[1][0][i][bb] + bf2f(ih[r])            + bhh0[r];
      float gf = gl[0][1][i][bb] + gl[1][1][i][bb] + bf2f(ih[HDIM + r])     + bhh0[HDIM + r];
      float gg = gl[0][2][i][bb] + gl[1][2][i][bb] + bf2f(ih[2 * HDIM + r]) + bhh0[2 * HDIM + r];
      float go = gl[0][3][i][bb] + gl[1][3][i][bb] + bf2f(ih[3 * HDIM + r]) + bhh0[3 * HDIM + r];
      float cn = sigm(gf) * c0[ci] + sigm(gi) * tanh_(gg);
      float hn = sigm(go) * tanh_(cn);
      c0[ci] = cn;
      h0_out[hpk(r, bb)] = f2bf(hn);
    }
    gridbar(cnt, gen);

    // ---------------- layer 1 ----------------
    {
      f32x4 acc[4] = {};
      gemmP(pWih1 + wo, h0_out, kc0, kc1, lane, lr, lg, acc);
      gemmP(pWhh1 + wo, h1_in,  kc0, kc1, lane, lr, lg, acc);
      if (kq < 2) {
        #pragma unroll
        for (int n0 = 0; n0 < 4; ++n0)
          #pragma unroll
          for (int e = 0; e < 4; ++e)
            gl[kq][gate][4 * lg + e][(n0 << 4) + lr] = acc[n0][e];
      }
      __syncthreads();
      if (kq >= 2) {
        #pragma unroll
        for (int n0 = 0; n0 < 4; ++n0)
          #pragma unroll
          for (int e = 0; e < 4; ++e)
            gl[kq - 2][gate][4 * lg + e][(n0 << 4) + lr] += acc[n0][e];
      }
      __syncthreads();
      float gi = gl[0][0][i][bb] + gl[1][0][i][bb] + bih1[r]            + bhh1[r];
      float gf = gl[0][1][i][bb] + gl[1][1][i][bb] + bih1[HDIM + r]     + bhh1[HDIM + r];
      float gg = gl[0][2][i][bb] + gl[1][2][i][bb] + bih1[2 * HDIM + r] + bhh1[2 * HDIM + r];
      float go = gl[0][3][i][bb] + gl[1][3][i][bb] + bih1[3 * HDIM + r] + bhh1[3 * HDIM + r];
      float cn = sigm(gf) * c1[ci] + sigm(gi) * tanh_(gg);
      float hn = sigm(go) * tanh_(cn);
      c1[ci] = cn;
      h1_out[hpk(r, bb)] = f2bf(hn);
      out[(size_t)bb * (32 * HDIM) + (size_t)(t + 1) * HDIM + r] = hn;
    }
    gridbar(cnt, gen);
  }
}

__global__ void sentinel_k(float* o) { o[0] = -123456.f; }

extern "C" void kernel_launch(void* const* d_in, const int* in_sizes, int n_in,
                              void* d_out, int out_size, void* d_ws, size_t ws_size,
                              hipStream_t stream) {
  (void)in_sizes; (void)n_in;
  const float* features = (const float*)d_in[0];
  const int*   captions = (const int*)d_in[1];
  const float* W_ih0    = (const float*)d_in[2];
  const float* W_hh0    = (const float*)d_in[3];
  const float* b_ih0    = (const float*)d_in[4];
  const float* b_hh0    = (const float*)d_in[5];
  const float* W_ih1    = (const float*)d_in[6];
  const float* W_hh1    = (const float*)d_in[7];
  const float* b_ih1    = (const float*)d_in[8];
  const float* b_hh1    = (const float*)d_in[9];
  float* out = (float*)d_out;

  char* w = (char*)d_ws;
  unsigned short* h0b   = (unsigned short*)(w);                 // 2 x 256000 elems, packed
  unsigned short* h1b   = (unsigned short*)(w + 1024000);
  float*          c0    = (float*)(w + 2048000);
  float*          c1    = (float*)(w + 3072000);
  unsigned short* pWhh0 = (unsigned short*)(w + 4096000);
  unsigned short* pWih1 = (unsigned short*)(w + 132096000);
  unsigned short* pWhh1 = (unsigned short*)(w + 260096000);
  unsigned short* bWf   = (unsigned short*)(w + 388096000);
  unsigned short* ih0T  = (unsigned short*)(w + 420864000);     // [16000][1984]
  float*          fp0   = (float*)(w + 484352000);
  unsigned short* bFeat = (unsigned short*)(w + 488448000);
  unsigned*       bar   = (unsigned*)(w + 488579072);           // 256 B
  unsigned short* ih0J  = (unsigned short*)(w + 488579328);     // [1984][16000]
  const size_t NEED = 552067328;
  if (ws_size < NEED) { sentinel_k<<<1, 1, 0, stream>>>(out); return; }

  hipMemsetAsync(d_out, 0, (size_t)out_size * 4, stream);  // also provides out[:,0,:]=0
  hipMemsetAsync(w, 0, 4096000, stream);                   // h/c initial state = 0
  hipMemsetAsync(w + 488579072, 0, 256, stream);           // barrier state

  pack_k<<<31250, 256, 0, stream>>>(W_hh0, pWhh0);
  pack_k<<<31250, 256, 0, stream>>>(W_ih1, pWih1);
  pack_k<<<31250, 256, 0, stream>>>(W_hh1, pWhh1);
  to_bf16_k<<<32,    256, 0, stream>>>(features, bFeat, 65536L);
  wf_conv_k<<<8000,  256, 0, stream>>>(W_ih0, bWf);
  featpre_k<<<250,   512, 0, stream>>>(bWf, bFeat, b_ih0, fp0);
  gather_k<<<4000,   256, 0, stream>>>(W_ih0, captions, fp0, ih0T);
  tj_k<<<dim3(500, 62), 256, 0, stream>>>(ih0T, ih0J);

  lstm_persist_k<<<NBLK, 1024, 0, stream>>>(pWhh0, pWih1, pWhh1, h0b, h1b, c0, c1,
                                            ih0J, b_hh0, b_ih1, b_hh1, out, bar);
}

// Round 5
// 3631.690 us; speedup vs baseline: 1.4422x; 1.4422x over previous
//
#include <hip/hip_runtime.h>

#define DEVINL __device__ __forceinline__

typedef __attribute__((ext_vector_type(4))) float f32x4;
typedef __attribute__((ext_vector_type(8))) short s16x8;
typedef __attribute__((ext_vector_type(4))) unsigned short u16x4;
typedef __attribute__((ext_vector_type(8))) unsigned short u16x8;

static constexpr int HDIM = 4000;    // hidden
static constexpr int G4   = 16000;   // 4*H
static constexpr int FD   = 1024;    // feature dim
static constexpr int LD0  = 5024;    // W_ih0 row stride
static constexpr int TT   = 31;      // timesteps computed
static constexpr int NJ   = 64 * 31; // (b,t) pairs
static constexpr int KCT  = 125;     // k-chunks (32 wide) per K=4000

DEVINL float bf2f(unsigned short u) {
  unsigned v = (unsigned)u << 16;
  return __builtin_bit_cast(float, v);
}
DEVINL unsigned short f2bf(float x) {
  unsigned u = __builtin_bit_cast(unsigned, x);
  u += 0x7fffu + ((u >> 16) & 1u);          // RNE, no NaNs in this problem
  return (unsigned short)(u >> 16);
}
DEVINL float sigm(float x) { return 1.f / (1.f + __expf(-x)); }
DEVINL float tanh_(float x) { float e = __expf(2.f * x); return (e - 1.f) / (e + 1.f); }

// ---------- packed-layout GEMM ----------
// A: pW chunk layout [o][lane][8], o = (rb*4+g)*125 + kc.  1 KB/instr, sequential.
// B: hP layout [k8][64][8]; 4 frags of one iter = one contiguous 4 KB span.
// k-permutation (k = 8*lg+e within chunk) identical on A and B -> cancels.
DEVINL void gemmP(const unsigned short* __restrict__ Wp,
                  const unsigned short* __restrict__ hP,
                  int kc0, int kc1, int lane, int lr, int lg, f32x4* acc) {
  const unsigned short* wp = Wp + (size_t)kc0 * 512 + lane * 8;
  const unsigned short* bp = hP + (size_t)kc0 * 2048 + (lg * 64 + lr) * 8;
  #pragma unroll 2
  for (int kc = kc0; kc < kc1; ++kc) {
    s16x8 a  = *(const s16x8*)wp;
    s16x8 b0 = *(const s16x8*)(bp);
    s16x8 b1 = *(const s16x8*)(bp + 128);
    s16x8 b2 = *(const s16x8*)(bp + 256);
    s16x8 b3 = *(const s16x8*)(bp + 384);
    wp += 512; bp += 2048;
    acc[0] = __builtin_amdgcn_mfma_f32_16x16x32_bf16(a, b0, acc[0], 0, 0, 0);
    acc[1] = __builtin_amdgcn_mfma_f32_16x16x32_bf16(a, b1, acc[1], 0, 0, 0);
    acc[2] = __builtin_amdgcn_mfma_f32_16x16x32_bf16(a, b2, acc[2], 0, 0, 0);
    acc[3] = __builtin_amdgcn_mfma_f32_16x16x32_bf16(a, b3, acc[3], 0, 0, 0);
  }
}

// ---------- row-major-B GEMM (featpre only) ----------
DEVINL void gemm16u(const unsigned short* __restrict__ W,
                    const unsigned short* __restrict__ Hb,
                    int K, int kbeg, int kend, int lr, int lg, f32x4* acc) {
  const unsigned short* wp  = W  + (size_t)lr * K + 8 * lg + kbeg;
  const unsigned short* hp0 = Hb + (size_t)lr * K + 8 * lg + kbeg;
  const unsigned short* hp1 = hp0 + (size_t)16 * K;
  const unsigned short* hp2 = hp0 + (size_t)32 * K;
  const unsigned short* hp3 = hp0 + (size_t)48 * K;
  int nk = kend - kbeg;
  #pragma unroll 2
  for (int k = 0; k < nk; k += 32) {
    s16x8 a  = *(const s16x8*)(wp  + k);
    s16x8 b0 = *(const s16x8*)(hp0 + k);
    s16x8 b1 = *(const s16x8*)(hp1 + k);
    s16x8 b2 = *(const s16x8*)(hp2 + k);
    s16x8 b3 = *(const s16x8*)(hp3 + k);
    acc[0] = __builtin_amdgcn_mfma_f32_16x16x32_bf16(a, b0, acc[0], 0, 0, 0);
    acc[1] = __builtin_amdgcn_mfma_f32_16x16x32_bf16(a, b1, acc[1], 0, 0, 0);
    acc[2] = __builtin_amdgcn_mfma_f32_16x16x32_bf16(a, b2, acc[2], 0, 0, 0);
    acc[3] = __builtin_amdgcn_mfma_f32_16x16x32_bf16(a, b3, acc[3], 0, 0, 0);
  }
}

__global__ void to_bf16_k(const float* __restrict__ s, unsigned short* __restrict__ d, long n) {
  long i = (((long)blockIdx.x * blockDim.x) + threadIdx.x) * 8;
  if (i >= n) return;
  f32x4 a = *(const f32x4*)(s + i);
  f32x4 b = *(const f32x4*)(s + i + 4);
  u16x8 o;
  o[0] = f2bf(a[0]); o[1] = f2bf(a[1]); o[2] = f2bf(a[2]); o[3] = f2bf(a[3]);
  o[4] = f2bf(b[0]); o[5] = f2bf(b[1]); o[6] = f2bf(b[2]); o[7] = f2bf(b[3]);
  *(u16x8*)(d + i) = o;
}

// pack W [16000][4000] f32 -> fragment-linear bf16 chunks
__global__ __launch_bounds__(256) void pack_k(const float* __restrict__ W,
                                              unsigned short* __restrict__ P) {
  int wv = (blockIdx.x << 2) + (threadIdx.x >> 6);    // chunk id 0..124999
  int lane = threadIdx.x & 63, lr = lane & 15, lg = lane >> 4;
  int rb = wv / 500; int rem = wv - rb * 500;
  int g = rem / KCT; int kc = rem - g * KCT;
  int row = g * 4000 + rb * 16 + lr;
  int col = kc * 32 + lg * 8;
  const float* sp = W + (size_t)row * 4000 + col;
  f32x4 a = *(const f32x4*)sp;
  f32x4 b = *(const f32x4*)(sp + 4);
  u16x8 o;
  o[0] = f2bf(a[0]); o[1] = f2bf(a[1]); o[2] = f2bf(a[2]); o[3] = f2bf(a[3]);
  o[4] = f2bf(b[0]); o[5] = f2bf(b[1]); o[6] = f2bf(b[2]); o[7] = f2bf(b[3]);
  *(u16x8*)(P + ((size_t)wv * 64 + lane) * 8) = o;
}

// W_f = W_ih0[:, :1024] (strided rows) -> bf16 [16000][1024]
__global__ void wf_conv_k(const float* __restrict__ s, unsigned short* __restrict__ d) {
  int idx = blockIdx.x * blockDim.x + threadIdx.x;   // 16000*128
  int r = idx >> 7;
  int k8 = (idx & 127) << 3;
  const float* sp = s + (size_t)r * LD0 + k8;
  f32x4 a = *(const f32x4*)sp;
  f32x4 b = *(const f32x4*)(sp + 4);
  u16x8 o;
  o[0] = f2bf(a[0]); o[1] = f2bf(a[1]); o[2] = f2bf(a[2]); o[3] = f2bf(a[3]);
  o[4] = f2bf(b[0]); o[5] = f2bf(b[1]); o[6] = f2bf(b[2]); o[7] = f2bf(b[3]);
  *(u16x8*)(d + (size_t)r * FD + k8) = o;
}

// fp0[b][r] = b_ih0[r] + sum_k feat[b][k] * Wf[r][k]
__global__ __launch_bounds__(512, 2) void featpre_k(
    const unsigned short* __restrict__ Wf, const unsigned short* __restrict__ Fb,
    const float* __restrict__ bih0, float* __restrict__ fp0) {
  __shared__ float gl[2][4][16][64];
  int tid = threadIdx.x, lane = tid & 63, wid = tid >> 6;
  int lr = lane & 15, lg = lane >> 4;
  int sub = wid & 3, kh = wid >> 2;
  int rowblk = blockIdx.x << 6;
  size_t row0 = (size_t)rowblk + (sub << 4);
  f32x4 acc[4] = {};
  gemm16u(Wf + row0 * FD, Fb, FD, kh ? 512 : 0, kh ? 1024 : 512, lr, lg, acc);
  #pragma unroll
  for (int n0 = 0; n0 < 4; ++n0)
    #pragma unroll
    for (int e = 0; e < 4; ++e)
      gl[kh][sub][4 * lg + e][(n0 << 4) + lr] = acc[n0][e];
  __syncthreads();
  for (int n = tid; n < 4096; n += 512) {
    int i = n & 63, b = n >> 6;
    int r = rowblk + i;
    float v = gl[0][i >> 4][i & 15][b] + gl[1][i >> 4][i & 15][b] + bih0[r];
    fp0[(size_t)b * G4 + r] = v;
  }
}

// ih0T[r][j] = bf16( fp0[b][r] + W_v[r][tok(b,t)] ), j = b*31+t  (coalesced)
__global__ __launch_bounds__(256) void gather_k(
    const float* __restrict__ Wih0, const int* __restrict__ caps,
    const float* __restrict__ fp0, unsigned short* __restrict__ ih0T) {
  __shared__ unsigned short wv[4][4000];
  int r0 = blockIdx.x << 2;
  for (int rr = 0; rr < 4; ++rr) {
    const float* src = Wih0 + (size_t)(r0 + rr) * LD0 + FD;
    for (int c4 = threadIdx.x; c4 < 1000; c4 += 256) {
      f32x4 v = *(const f32x4*)(src + c4 * 4);
      u16x4 o;
      o[0] = f2bf(v[0]); o[1] = f2bf(v[1]); o[2] = f2bf(v[2]); o[3] = f2bf(v[3]);
      *(u16x4*)(&wv[rr][c4 * 4]) = o;
    }
  }
  __syncthreads();
  for (int j = threadIdx.x; j < NJ; j += 256) {
    int b = j / TT, t = j - b * TT;
    int tok = caps[(b << 5) + t];
    f32x4 f = *(const f32x4*)(fp0 + (size_t)b * G4 + r0);
    #pragma unroll
    for (int rr = 0; rr < 4; ++rr)
      ih0T[(size_t)(r0 + rr) * NJ + j] = f2bf(f[rr] + bf2f(wv[rr][tok]));
  }
}

// transpose ih0T [16000][1984] -> ih0J [1984][16000]
__global__ __launch_bounds__(256) void tj_k(const unsigned short* __restrict__ src,
                                            unsigned short* __restrict__ dst) {
  __shared__ unsigned short tile[32][34];
  int r0 = blockIdx.x << 5;      // 500 tiles
  int j0 = blockIdx.y << 5;      // 62 tiles
  int c = threadIdx.x & 31, q = threadIdx.x >> 5;
  #pragma unroll
  for (int e = 0; e < 4; ++e) {
    int rr = q + e * 8;
    tile[rr][c] = src[(size_t)(r0 + rr) * NJ + j0 + c];
  }
  __syncthreads();
  #pragma unroll
  for (int e = 0; e < 4; ++e) {
    int jj = q + e * 8;
    dst[(size_t)(j0 + jj) * G4 + r0 + c] = tile[c][jj];
  }
}

DEVINL size_t hpk(int r, int b) {          // packed h index [k8][64][8]
  return ((size_t)(r >> 3) * 64 + b) * 8 + (r & 7);
}

// Phase p (p = 0..31): computes l0 for t=p (if p<31) and l1 for t=p-1 (if p>=1).
// The two parts are independent: l0(p) needs h0_{p-1}; l1(p-1) needs h0_{p-1},
// h1_{p-2} — all produced in earlier dispatches (HW grid barrier = kernel edge).
// h0_t lives in h0b[t&1]; h1_t in h1b[t&1].
__global__ __launch_bounds__(1024, 1) void fused_step_k(
    const unsigned short* __restrict__ pWhh0, const unsigned short* __restrict__ pWih1,
    const unsigned short* __restrict__ pWhh1,
    unsigned short* __restrict__ h0b, unsigned short* __restrict__ h1b,
    float* __restrict__ c0, float* __restrict__ c1,
    const unsigned short* __restrict__ ih0J,
    const float* __restrict__ bhh0, const float* __restrict__ bih1,
    const float* __restrict__ bhh1, float* __restrict__ out, int p) {
  __shared__ float gl[2][4][16][64];
  int tid = threadIdx.x, lane = tid & 63, wid = tid >> 6;   // wid 0..15
  int lr = lane & 15, lg = lane >> 4;
  int gate = wid & 3, kq = wid >> 2;
  int wg16 = blockIdx.x << 4;
  int kc0 = 31 * kq, kc1 = (kq == 3) ? KCT : kc0 + 31;
  int i = tid & 15, bb = tid >> 4;                          // epilogue mapping
  int r = wg16 + i;
  size_t ci = (size_t)bb * HDIM + r;
  size_t wo = ((size_t)(blockIdx.x * 4 + gate) * KCT) * 512;

  // ---------------- layer 0, t = p ----------------
  if (p < TT) {
    const unsigned short* h0_in = h0b + (size_t)((p ^ 1) & 1) * 256000;  // h0_{p-1}
    unsigned short* h0_out      = h0b + (size_t)(p & 1) * 256000;        // h0_p
    f32x4 acc[4] = {};
    if (p > 0)                                    // h0_{-1} == 0: skip 128 MB read
      gemmP(pWhh0 + wo, h0_in, kc0, kc1, lane, lr, lg, acc);
    if (kq < 2) {
      #pragma unroll
      for (int n0 = 0; n0 < 4; ++n0)
        #pragma unroll
        for (int e = 0; e < 4; ++e)
          gl[kq][gate][4 * lg + e][(n0 << 4) + lr] = acc[n0][e];
    }
    __syncthreads();
    if (kq >= 2) {
      #pragma unroll
      for (int n0 = 0; n0 < 4; ++n0)
        #pragma unroll
        for (int e = 0; e < 4; ++e)
          gl[kq - 2][gate][4 * lg + e][(n0 << 4) + lr] += acc[n0][e];
    }
    __syncthreads();
    const unsigned short* ih = ih0J + (size_t)(bb * TT + p) * G4;
    float gi = gl[0][0][i][bb] + gl[1][0][i][bb] + bf2f(ih[r])            + bhh0[r];
    float gf = gl[0][1][i][bb] + gl[1][1][i][bb] + bf2f(ih[HDIM + r])     + bhh0[HDIM + r];
    float gg = gl[0][2][i][bb] + gl[1][2][i][bb] + bf2f(ih[2 * HDIM + r]) + bhh0[2 * HDIM + r];
    float go = gl[0][3][i][bb] + gl[1][3][i][bb] + bf2f(ih[3 * HDIM + r]) + bhh0[3 * HDIM + r];
    float cn = sigm(gf) * c0[ci] + sigm(gi) * tanh_(gg);
    float hn = sigm(go) * tanh_(cn);
    c0[ci] = cn;
    h0_out[hpk(r, bb)] = f2bf(hn);
    __syncthreads();                              // gl reads done before l1 reuses
  }

  // ---------------- layer 1, t = p-1 ----------------
  if (p >= 1) {
    int t = p - 1;
    const unsigned short* h0_t  = h0b + (size_t)(t & 1) * 256000;        // h0_{p-1}
    const unsigned short* h1_in = h1b + (size_t)((t ^ 1) & 1) * 256000;  // h1_{p-2}
    unsigned short* h1_out      = h1b + (size_t)(t & 1) * 256000;        // h1_{p-1}
    f32x4 acc[4] = {};
    gemmP(pWih1 + wo, h0_t, kc0, kc1, lane, lr, lg, acc);
    if (t > 0)                                    // h1_{-1} == 0
      gemmP(pWhh1 + wo, h1_in, kc0, kc1, lane, lr, lg, acc);
    if (kq < 2) {
      #pragma unroll
      for (int n0 = 0; n0 < 4; ++n0)
        #pragma unroll
        for (int e = 0; e < 4; ++e)
          gl[kq][gate][4 * lg + e][(n0 << 4) + lr] = acc[n0][e];
    }
    __syncthreads();
    if (kq >= 2) {
      #pragma unroll
      for (int n0 = 0; n0 < 4; ++n0)
        #pragma unroll
        for (int e = 0; e < 4; ++e)
          gl[kq - 2][gate][4 * lg + e][(n0 << 4) + lr] += acc[n0][e];
    }
    __syncthreads();
    float gi = gl[0][0][i][bb] + gl[1][0][i][bb] + bih1[r]            + bhh1[r];
    float gf = gl[0][1][i][bb] + gl[1][1][i][bb] + bih1[HDIM + r]     + bhh1[HDIM + r];
    float gg = gl[0][2][i][bb] + gl[1][2][i][bb] + bih1[2 * HDIM + r] + bhh1[2 * HDIM + r];
    float go = gl[0][3][i][bb] + gl[1][3][i][bb] + bih1[3 * HDIM + r] + bhh1[3 * HDIM + r];
    float cn = sigm(gf) * c1[ci] + sigm(gi) * tanh_(gg);
    float hn = sigm(go) * tanh_(cn);
    c1[ci] = cn;
    h1_out[hpk(r, bb)] = f2bf(hn);
    out[(size_t)bb * (32 * HDIM) + (size_t)(t + 1) * HDIM + r] = hn;
  }
}

__global__ void sentinel_k(float* o) { o[0] = -123456.f; }

extern "C" void kernel_launch(void* const* d_in, const int* in_sizes, int n_in,
                              void* d_out, int out_size, void* d_ws, size_t ws_size,
                              hipStream_t stream) {
  (void)in_sizes; (void)n_in;
  const float* features = (const float*)d_in[0];
  const int*   captions = (const int*)d_in[1];
  const float* W_ih0    = (const float*)d_in[2];
  const float* W_hh0    = (const float*)d_in[3];
  const float* b_ih0    = (const float*)d_in[4];
  const float* b_hh0    = (const float*)d_in[5];
  const float* W_ih1    = (const float*)d_in[6];
  const float* W_hh1    = (const float*)d_in[7];
  const float* b_ih1    = (const float*)d_in[8];
  const float* b_hh1    = (const float*)d_in[9];
  float* out = (float*)d_out;

  char* w = (char*)d_ws;
  unsigned short* h0b   = (unsigned short*)(w);                 // 2 x 256000 elems, packed
  unsigned short* h1b   = (unsigned short*)(w + 1024000);
  float*          c0    = (float*)(w + 2048000);
  float*          c1    = (float*)(w + 3072000);
  unsigned short* pWhh0 = (unsigned short*)(w + 4096000);
  unsigned short* pWih1 = (unsigned short*)(w + 132096000);
  unsigned short* pWhh1 = (unsigned short*)(w + 260096000);
  unsigned short* bWf   = (unsigned short*)(w + 388096000);
  unsigned short* ih0T  = (unsigned short*)(w + 420864000);     // [16000][1984]
  float*          fp0   = (float*)(w + 484352000);
  unsigned short* bFeat = (unsigned short*)(w + 488448000);
  unsigned short* ih0J  = (unsigned short*)(w + 488579328);     // [1984][16000]
  const size_t NEED = 552067328;
  if (ws_size < NEED) { sentinel_k<<<1, 1, 0, stream>>>(out); return; }

  hipMemsetAsync(d_out, 0, (size_t)out_size * 4, stream);  // also provides out[:,0,:]=0
  hipMemsetAsync(w, 0, 4096000, stream);                   // h/c initial state = 0

  pack_k<<<31250, 256, 0, stream>>>(W_hh0, pWhh0);
  pack_k<<<31250, 256, 0, stream>>>(W_ih1, pWih1);
  pack_k<<<31250, 256, 0, stream>>>(W_hh1, pWhh1);
  to_bf16_k<<<32,    256, 0, stream>>>(features, bFeat, 65536L);
  wf_conv_k<<<8000,  256, 0, stream>>>(W_ih0, bWf);
  featpre_k<<<250,   512, 0, stream>>>(bWf, bFeat, b_ih0, fp0);
  gather_k<<<4000,   256, 0, stream>>>(W_ih0, captions, fp0, ih0T);
  tj_k<<<dim3(500, 62), 256, 0, stream>>>(ih0T, ih0J);

  for (int p = 0; p <= TT; ++p) {
    fused_step_k<<<250, 1024, 0, stream>>>(pWhh0, pWih1, pWhh1, h0b, h1b, c0, c1,
                                           ih0J, b_hh0, b_ih1, b_hh1, out, p);
  }
}

// Round 6
// 2865.436 us; speedup vs baseline: 1.8279x; 1.2674x over previous
//
#include <hip/hip_runtime.h>

#define DEVINL __device__ __forceinline__

typedef __attribute__((ext_vector_type(4))) float f32x4;
typedef __attribute__((ext_vector_type(8))) short s16x8;
typedef __attribute__((ext_vector_type(4))) unsigned short u16x4;
typedef __attribute__((ext_vector_type(8))) unsigned short u16x8;

static constexpr int HDIM = 4000;    // hidden
static constexpr int G4   = 16000;   // 4*H
static constexpr int FD   = 1024;    // feature dim
static constexpr int LD0  = 5024;    // W_ih0 row stride
static constexpr int TT   = 31;      // timesteps computed
static constexpr int NJ   = 64 * 31; // (b,t) pairs
static constexpr int KCT  = 125;     // k-chunks (32 wide) per K=4000

DEVINL float bf2f(unsigned short u) {
  unsigned v = (unsigned)u << 16;
  return __builtin_bit_cast(float, v);
}
DEVINL unsigned short f2bf(float x) {
  unsigned u = __builtin_bit_cast(unsigned, x);
  u += 0x7fffu + ((u >> 16) & 1u);          // RNE, no NaNs in this problem
  return (unsigned short)(u >> 16);
}
DEVINL float sigm(float x) { return 1.f / (1.f + __expf(-x)); }
DEVINL float tanh_(float x) { float e = __expf(2.f * x); return (e - 1.f) / (e + 1.f); }

#define MFMA_BF16 __builtin_amdgcn_mfma_f32_16x16x32_bf16

// 2 A-fragments (gate pair) x 4 B-fragments -> 8 MFMAs
DEVINL void mfma8(s16x8 a0, s16x8 a1, const unsigned short* __restrict__ bp,
                  f32x4 acc[2][4]) {
  s16x8 b0 = *(const s16x8*)(bp);
  s16x8 b1 = *(const s16x8*)(bp + 128);
  s16x8 b2 = *(const s16x8*)(bp + 256);
  s16x8 b3 = *(const s16x8*)(bp + 384);
  acc[0][0] = MFMA_BF16(a0, b0, acc[0][0], 0, 0, 0);
  acc[0][1] = MFMA_BF16(a0, b1, acc[0][1], 0, 0, 0);
  acc[0][2] = MFMA_BF16(a0, b2, acc[0][2], 0, 0, 0);
  acc[0][3] = MFMA_BF16(a0, b3, acc[0][3], 0, 0, 0);
  acc[1][0] = MFMA_BF16(a1, b0, acc[1][0], 0, 0, 0);
  acc[1][1] = MFMA_BF16(a1, b1, acc[1][1], 0, 0, 0);
  acc[1][2] = MFMA_BF16(a1, b2, acc[1][2], 0, 0, 0);
  acc[1][3] = MFMA_BF16(a1, b3, acc[1][3], 0, 0, 0);
}

// gate-pair GEMM over [kc0,kc1), optional reverse (palindromic streaming)
DEVINL void gpair(const unsigned short* __restrict__ W0,
                  const unsigned short* __restrict__ W1,
                  const unsigned short* __restrict__ hP,
                  int kc0, int kc1, int dir, int lane, int lr, int lg,
                  f32x4 acc[2][4]) {
  int n = kc1 - kc0;
  #pragma unroll 2
  for (int s = 0; s < n; ++s) {
    int kc = dir ? (kc1 - 1 - s) : (kc0 + s);
    s16x8 a0 = *(const s16x8*)(W0 + (size_t)kc * 512 + lane * 8);
    s16x8 a1 = *(const s16x8*)(W1 + (size_t)kc * 512 + lane * 8);
    mfma8(a0, a1, hP + (size_t)kc * 2048 + (lg * 64 + lr) * 8, acc);
  }
}

// fused l1 GEMM: acc += Wih1*h0 (+ Whh1*h1 if HH), interleaved at kc grain
template <bool HH>
DEVINL void gpair2(const unsigned short* __restrict__ Wi0,
                   const unsigned short* __restrict__ Wi1,
                   const unsigned short* __restrict__ Wh0,
                   const unsigned short* __restrict__ Wh1,
                   const unsigned short* __restrict__ h0P,
                   const unsigned short* __restrict__ h1P,
                   int kc0, int kc1, int dir, int lane, int lr, int lg,
                   f32x4 acc[2][4]) {
  int n = kc1 - kc0;
  #pragma unroll 1
  for (int s = 0; s < n; ++s) {
    int kc = dir ? (kc1 - 1 - s) : (kc0 + s);
    size_t woff = (size_t)kc * 512 + lane * 8;
    size_t boff = (size_t)kc * 2048 + (lg * 64 + lr) * 8;
    s16x8 ai0 = *(const s16x8*)(Wi0 + woff);
    s16x8 ai1 = *(const s16x8*)(Wi1 + woff);
    mfma8(ai0, ai1, h0P + boff, acc);
    if (HH) {
      s16x8 ah0 = *(const s16x8*)(Wh0 + woff);
      s16x8 ah1 = *(const s16x8*)(Wh1 + woff);
      mfma8(ah0, ah1, h1P + boff, acc);
    }
  }
}

// 8-partial reduction into gl[2][4][16][64]; 4 rounds, sync each
DEVINL void reduce_acc(float gl[2][4][16][64], f32x4 acc[2][4],
                       int gp, int kq, int lr, int lg) {
  for (int rnd = 0; rnd < 4; ++rnd) {
    if ((kq >> 1) == rnd) {
      int slot = kq & 1;
      #pragma unroll
      for (int j = 0; j < 2; ++j) {
        int g = 2 * gp + j;
        #pragma unroll
        for (int n0 = 0; n0 < 4; ++n0)
          #pragma unroll
          for (int e = 0; e < 4; ++e) {
            float* d = &gl[slot][g][4 * lg + e][(n0 << 4) + lr];
            if (rnd == 0) *d = acc[j][n0][e];
            else          *d += acc[j][n0][e];
          }
      }
    }
    __syncthreads();
  }
}

__global__ void to_bf16_k(const float* __restrict__ s, unsigned short* __restrict__ d, long n) {
  long i = (((long)blockIdx.x * blockDim.x) + threadIdx.x) * 8;
  if (i >= n) return;
  f32x4 a = *(const f32x4*)(s + i);
  f32x4 b = *(const f32x4*)(s + i + 4);
  u16x8 o;
  o[0] = f2bf(a[0]); o[1] = f2bf(a[1]); o[2] = f2bf(a[2]); o[3] = f2bf(a[3]);
  o[4] = f2bf(b[0]); o[5] = f2bf(b[1]); o[6] = f2bf(b[2]); o[7] = f2bf(b[3]);
  *(u16x8*)(d + i) = o;
}

// pack W [16000][4000] f32 -> fragment-linear bf16 chunks
__global__ __launch_bounds__(256) void pack_k(const float* __restrict__ W,
                                              unsigned short* __restrict__ P) {
  int wv = (blockIdx.x << 2) + (threadIdx.x >> 6);    // chunk id 0..124999
  int lane = threadIdx.x & 63, lr = lane & 15, lg = lane >> 4;
  int rb = wv / 500; int rem = wv - rb * 500;
  int g = rem / KCT; int kc = rem - g * KCT;
  int row = g * 4000 + rb * 16 + lr;
  int col = kc * 32 + lg * 8;
  const float* sp = W + (size_t)row * 4000 + col;
  f32x4 a = *(const f32x4*)sp;
  f32x4 b = *(const f32x4*)(sp + 4);
  u16x8 o;
  o[0] = f2bf(a[0]); o[1] = f2bf(a[1]); o[2] = f2bf(a[2]); o[3] = f2bf(a[3]);
  o[4] = f2bf(b[0]); o[5] = f2bf(b[1]); o[6] = f2bf(b[2]); o[7] = f2bf(b[3]);
  *(u16x8*)(P + ((size_t)wv * 64 + lane) * 8) = o;
}

// W_f = W_ih0[:, :1024] (strided rows) -> bf16 [16000][1024]
__global__ void wf_conv_k(const float* __restrict__ s, unsigned short* __restrict__ d) {
  int idx = blockIdx.x * blockDim.x + threadIdx.x;   // 16000*128
  int r = idx >> 7;
  int k8 = (idx & 127) << 3;
  const float* sp = s + (size_t)r * LD0 + k8;
  f32x4 a = *(const f32x4*)sp;
  f32x4 b = *(const f32x4*)(sp + 4);
  u16x8 o;
  o[0] = f2bf(a[0]); o[1] = f2bf(a[1]); o[2] = f2bf(a[2]); o[3] = f2bf(a[3]);
  o[4] = f2bf(b[0]); o[5] = f2bf(b[1]); o[6] = f2bf(b[2]); o[7] = f2bf(b[3]);
  *(u16x8*)(d + (size_t)r * FD + k8) = o;
}

// ---------- row-major-B GEMM (featpre only) ----------
DEVINL void gemm16u(const unsigned short* __restrict__ W,
                    const unsigned short* __restrict__ Hb,
                    int K, int kbeg, int kend, int lr, int lg, f32x4* acc) {
  const unsigned short* wp  = W  + (size_t)lr * K + 8 * lg + kbeg;
  const unsigned short* hp0 = Hb + (size_t)lr * K + 8 * lg + kbeg;
  const unsigned short* hp1 = hp0 + (size_t)16 * K;
  const unsigned short* hp2 = hp0 + (size_t)32 * K;
  const unsigned short* hp3 = hp0 + (size_t)48 * K;
  int nk = kend - kbeg;
  #pragma unroll 2
  for (int k = 0; k < nk; k += 32) {
    s16x8 a  = *(const s16x8*)(wp  + k);
    s16x8 b0 = *(const s16x8*)(hp0 + k);
    s16x8 b1 = *(const s16x8*)(hp1 + k);
    s16x8 b2 = *(const s16x8*)(hp2 + k);
    s16x8 b3 = *(const s16x8*)(hp3 + k);
    acc[0] = MFMA_BF16(a, b0, acc[0], 0, 0, 0);
    acc[1] = MFMA_BF16(a, b1, acc[1], 0, 0, 0);
    acc[2] = MFMA_BF16(a, b2, acc[2], 0, 0, 0);
    acc[3] = MFMA_BF16(a, b3, acc[3], 0, 0, 0);
  }
}

// fp0[b][r] = b_ih0[r] + sum_k feat[b][k] * Wf[r][k]
__global__ __launch_bounds__(512, 2) void featpre_k(
    const unsigned short* __restrict__ Wf, const unsigned short* __restrict__ Fb,
    const float* __restrict__ bih0, float* __restrict__ fp0) {
  __shared__ float gl[2][4][16][64];
  int tid = threadIdx.x, lane = tid & 63, wid = tid >> 6;
  int lr = lane & 15, lg = lane >> 4;
  int sub = wid & 3, kh = wid >> 2;
  int rowblk = blockIdx.x << 6;
  size_t row0 = (size_t)rowblk + (sub << 4);
  f32x4 acc[4] = {};
  gemm16u(Wf + row0 * FD, Fb, FD, kh ? 512 : 0, kh ? 1024 : 512, lr, lg, acc);
  #pragma unroll
  for (int n0 = 0; n0 < 4; ++n0)
    #pragma unroll
    for (int e = 0; e < 4; ++e)
      gl[kh][sub][4 * lg + e][(n0 << 4) + lr] = acc[n0][e];
  __syncthreads();
  for (int n = tid; n < 4096; n += 512) {
    int i = n & 63, b = n >> 6;
    int r = rowblk + i;
    float v = gl[0][i >> 4][i & 15][b] + gl[1][i >> 4][i & 15][b] + bih0[r];
    fp0[(size_t)b * G4 + r] = v;
  }
}

// ih0T[r][j] = bf16( fp0[b][r] + W_v[r][tok(b,t)] ), j = b*31+t  (coalesced)
__global__ __launch_bounds__(256) void gather_k(
    const float* __restrict__ Wih0, const int* __restrict__ caps,
    const float* __restrict__ fp0, unsigned short* __restrict__ ih0T) {
  __shared__ unsigned short wv[4][4000];
  int r0 = blockIdx.x << 2;
  for (int rr = 0; rr < 4; ++rr) {
    const float* src = Wih0 + (size_t)(r0 + rr) * LD0 + FD;
    for (int c4 = threadIdx.x; c4 < 1000; c4 += 256) {
      f32x4 v = *(const f32x4*)(src + c4 * 4);
      u16x4 o;
      o[0] = f2bf(v[0]); o[1] = f2bf(v[1]); o[2] = f2bf(v[2]); o[3] = f2bf(v[3]);
      *(u16x4*)(&wv[rr][c4 * 4]) = o;
    }
  }
  __syncthreads();
  for (int j = threadIdx.x; j < NJ; j += 256) {
    int b = j / TT, t = j - b * TT;
    int tok = caps[(b << 5) + t];
    f32x4 f = *(const f32x4*)(fp0 + (size_t)b * G4 + r0);
    #pragma unroll
    for (int rr = 0; rr < 4; ++rr)
      ih0T[(size_t)(r0 + rr) * NJ + j] = f2bf(f[rr] + bf2f(wv[rr][tok]));
  }
}

// transpose ih0T [16000][1984] -> ih0J [1984][16000]
__global__ __launch_bounds__(256) void tj_k(const unsigned short* __restrict__ src,
                                            unsigned short* __restrict__ dst) {
  __shared__ unsigned short tile[32][34];
  int r0 = blockIdx.x << 5;      // 500 tiles
  int j0 = blockIdx.y << 5;      // 62 tiles
  int c = threadIdx.x & 31, q = threadIdx.x >> 5;
  #pragma unroll
  for (int e = 0; e < 4; ++e) {
    int rr = q + e * 8;
    tile[rr][c] = src[(size_t)(r0 + rr) * NJ + j0 + c];
  }
  __syncthreads();
  #pragma unroll
  for (int e = 0; e < 4; ++e) {
    int jj = q + e * 8;
    dst[(size_t)(j0 + jj) * G4 + r0 + c] = tile[c][jj];
  }
}

DEVINL size_t hpk(int r, int b) {          // packed h index [k8][64][8]
  return ((size_t)(r >> 3) * 64 + b) * 8 + (r & 7);
}

// Phase p: l0 for t=p (p<31) and l1 for t=p-1 (p>=1); independent parts.
// dir=p&1: odd phases run l1 first and stream kc in reverse -> palindromic
// chip-wide weight stream maximizes L3 reuse across phase boundaries.
__global__ __launch_bounds__(1024, 1) void fused_step_k(
    const unsigned short* __restrict__ pWhh0, const unsigned short* __restrict__ pWih1,
    const unsigned short* __restrict__ pWhh1,
    unsigned short* __restrict__ h0b, unsigned short* __restrict__ h1b,
    float* __restrict__ c0, float* __restrict__ c1,
    const unsigned short* __restrict__ ih0J,
    const float* __restrict__ bhh0, const float* __restrict__ bih1,
    const float* __restrict__ bhh1, float* __restrict__ out, int p) {
  __shared__ float gl[2][4][16][64];
  int tid = threadIdx.x, lane = tid & 63, wid = tid >> 6;   // wid 0..15
  int lr = lane & 15, lg = lane >> 4;
  int gp = wid & 1, kq = wid >> 1;                          // 2 gate-pairs x 8 kq
  int kc0 = (kq * KCT) >> 3, kc1 = ((kq + 1) * KCT) >> 3;
  int dir = p & 1;
  int i = tid & 15, bb = tid >> 4;                          // epilogue mapping
  int r = (blockIdx.x << 4) + i;
  size_t ci = (size_t)bb * HDIM + r;
  // weight base for gates 2gp, 2gp+1 of this row-block
  size_t wo0 = ((size_t)(blockIdx.x * 4 + 2 * gp) * KCT) * 512;
  size_t wo1 = wo0 + (size_t)KCT * 512;

  for (int half = 0; half < 2; ++half) {
    bool run_l0 = (half == dir);          // dir=0: l0 first; dir=1: l1 first
    if (run_l0) {
      if (p >= TT) continue;
      const unsigned short* h0_in = h0b + (size_t)((p ^ 1) & 1) * 256000;  // h0_{p-1}
      unsigned short* h0_out      = h0b + (size_t)(p & 1) * 256000;        // h0_p
      f32x4 acc[2][4] = {};
      if (p > 0)                                  // h0_{-1}==0: skip stream
        gpair(pWhh0 + wo0, pWhh0 + wo1, h0_in, kc0, kc1, dir, lane, lr, lg, acc);
      reduce_acc(gl, acc, gp, kq, lr, lg);
      const unsigned short* ih = ih0J + (size_t)(bb * TT + p) * G4;
      float gi = gl[0][0][i][bb] + gl[1][0][i][bb] + bf2f(ih[r])            + bhh0[r];
      float gf = gl[0][1][i][bb] + gl[1][1][i][bb] + bf2f(ih[HDIM + r])     + bhh0[HDIM + r];
      float gg = gl[0][2][i][bb] + gl[1][2][i][bb] + bf2f(ih[2 * HDIM + r]) + bhh0[2 * HDIM + r];
      float go = gl[0][3][i][bb] + gl[1][3][i][bb] + bf2f(ih[3 * HDIM + r]) + bhh0[3 * HDIM + r];
      float cn = sigm(gf) * c0[ci] + sigm(gi) * tanh_(gg);
      float hn = sigm(go) * tanh_(cn);
      c0[ci] = cn;
      h0_out[hpk(r, bb)] = f2bf(hn);
      __syncthreads();                            // gl consumed before reuse
    } else {
      if (p < 1) continue;
      int t = p - 1;
      const unsigned short* h0_t  = h0b + (size_t)(t & 1) * 256000;        // h0_{p-1}
      const unsigned short* h1_in = h1b + (size_t)((t ^ 1) & 1) * 256000;  // h1_{p-2}
      unsigned short* h1_out      = h1b + (size_t)(t & 1) * 256000;        // h1_{p-1}
      f32x4 acc[2][4] = {};
      if (t > 0)
        gpair2<true>(pWih1 + wo0, pWih1 + wo1, pWhh1 + wo0, pWhh1 + wo1,
                     h0_t, h1_in, kc0, kc1, dir, lane, lr, lg, acc);
      else
        gpair2<false>(pWih1 + wo0, pWih1 + wo1, pWhh1 + wo0, pWhh1 + wo1,
                      h0_t, h1_in, kc0, kc1, dir, lane, lr, lg, acc);
      reduce_acc(gl, acc, gp, kq, lr, lg);
      float gi = gl[0][0][i][bb] + gl[1][0][i][bb] + bih1[r]            + bhh1[r];
      float gf = gl[0][1][i][bb] + gl[1][1][i][bb] + bih1[HDIM + r]     + bhh1[HDIM + r];
      float gg = gl[0][2][i][bb] + gl[1][2][i][bb] + bih1[2 * HDIM + r] + bhh1[2 * HDIM + r];
      float go = gl[0][3][i][bb] + gl[1][3][i][bb] + bih1[3 * HDIM + r] + bhh1[3 * HDIM + r];
      float cn = sigm(gf) * c1[ci] + sigm(gi) * tanh_(gg);
      float hn = sigm(go) * tanh_(cn);
      c1[ci] = cn;
      h1_out[hpk(r, bb)] = f2bf(hn);
      out[(size_t)bb * (32 * HDIM) + (size_t)(t + 1) * HDIM + r] = hn;
      __syncthreads();                            // gl consumed before reuse
    }
  }
}

__global__ void sentinel_k(float* o) { o[0] = -123456.f; }

extern "C" void kernel_launch(void* const* d_in, const int* in_sizes, int n_in,
                              void* d_out, int out_size, void* d_ws, size_t ws_size,
                              hipStream_t stream) {
  (void)in_sizes; (void)n_in;
  const float* features = (const float*)d_in[0];
  const int*   captions = (const int*)d_in[1];
  const float* W_ih0    = (const float*)d_in[2];
  const float* W_hh0    = (const float*)d_in[3];
  const float* b_ih0    = (const float*)d_in[4];
  const float* b_hh0    = (const float*)d_in[5];
  const float* W_ih1    = (const float*)d_in[6];
  const float* W_hh1    = (const float*)d_in[7];
  const float* b_ih1    = (const float*)d_in[8];
  const float* b_hh1    = (const float*)d_in[9];
  float* out = (float*)d_out;

  char* w = (char*)d_ws;
  unsigned short* h0b   = (unsigned short*)(w);                 // 2 x 256000 elems, packed
  unsigned short* h1b   = (unsigned short*)(w + 1024000);
  float*          c0    = (float*)(w + 2048000);
  float*          c1    = (float*)(w + 3072000);
  unsigned short* pWhh0 = (unsigned short*)(w + 4096000);
  unsigned short* pWih1 = (unsigned short*)(w + 132096000);
  unsigned short* pWhh1 = (unsigned short*)(w + 260096000);
  unsigned short* bWf   = (unsigned short*)(w + 388096000);
  unsigned short* ih0T  = (unsigned short*)(w + 420864000);     // [16000][1984]
  float*          fp0   = (float*)(w + 484352000);
  unsigned short* bFeat = (unsigned short*)(w + 488448000);
  unsigned short* ih0J  = (unsigned short*)(w + 488579328);     // [1984][16000]
  const size_t NEED = 552067328;
  if (ws_size < NEED) { sentinel_k<<<1, 1, 0, stream>>>(out); return; }

  hipMemsetAsync(d_out, 0, (size_t)out_size * 4, stream);  // also provides out[:,0,:]=0
  hipMemsetAsync(w, 0, 4096000, stream);                   // h/c initial state = 0

  pack_k<<<31250, 256, 0, stream>>>(W_hh0, pWhh0);
  pack_k<<<31250, 256, 0, stream>>>(W_ih1, pWih1);
  pack_k<<<31250, 256, 0, stream>>>(W_hh1, pWhh1);
  to_bf16_k<<<32,    256, 0, stream>>>(features, bFeat, 65536L);
  wf_conv_k<<<8000,  256, 0, stream>>>(W_ih0, bWf);
  featpre_k<<<250,   512, 0, stream>>>(bWf, bFeat, b_ih0, fp0);
  gather_k<<<4000,   256, 0, stream>>>(W_ih0, captions, fp0, ih0T);
  tj_k<<<dim3(500, 62), 256, 0, stream>>>(ih0T, ih0J);

  for (int p = 0; p <= TT; ++p) {
    fused_step_k<<<250, 1024, 0, stream>>>(pWhh0, pWih1, pWhh1, h0b, h1b, c0, c1,
                                           ih0J, b_hh0, b_ih1, b_hh1, out, p);
  }
}